// Round 2
// baseline (522.178 us; speedup 1.0000x reference)
//
#include <hip/hip_runtime.h>

// Laplacian pyramid L1 loss, (32,3,512,512) fp32, 5 levels.
// pyramid(in)-pyramid(tg) == pyramid(in-tg) (linearity) -> one pyramid.
// upsample(conv 4K on zero-stuffed) == polyphase on down:
//   even phase taps (.125,.75,.125), odd phase (.5,.5) per axis.
// lap_slide: wave-owned line-sliding pipeline. One wave = one R-row strip.
// Lane owns NC=W/64 cols. Horizontal 5-tap via shuffles, vertical via 5-row
// register ring, up via 3-row W ring. Next iteration's rows prefetched one
// full iteration ahead.
// ROUND-2 CHANGE: pending-accumulator band state. Old kernel kept
// {w0,w1,w2}+{eOld,eMid,oPrev} = 48 VGPRs (NC=8); VGPR_Count=76 landed in
// the (64,128] occupancy bin = 4 waves/SIMD cap (m69: waves halve at
// 64/128/256) -> 16 waves/CU cap explains round-1's flat occupancy/duration.
// New state {wPrev,pA,pB,pC} = 32 VGPRs: band row r is born as
// raw(r) - partial_up as soon as its raw row and the first W rows coexist,
// finalized 1-2 iters later:
//   pA (even row 2d-2) = raw - 0.125*W[d-2]; final: -0.75*W[d-1]-0.125*W[d]
//   pB (odd  row 2d-1) = raw - 0.5*W[d-1];   final: -0.5*W[d]
//   pC = next pA, created from c2 each iter.
// Boundaries: ye==0: pA=raw0 (prologue), final 0.75*wPrev+0.25*wN;
//             ye==H-2: final 0.875*wPrev (even), 0.5*wPrev (odd).
// __launch_bounds__(256,8) pins VGPR<=64 -> 8 waves/SIMD bin -> the
// 24-waves/CU grid actually becomes resident (MLP was the limiter:
// delivered BW ~4.9 TB/s at 16 waves/CU vs 6.3 ceiling).
// L1/L2 reverted to R=8/R=4 (round-1 halving was pure amplification loss).
// lap_small: levels 3+4, one 1024-thr block per plane.

#define BC 96
#define KA 0.0625f
#define KB 0.25f
#define KC 0.375f

__device__ __forceinline__ int refl(int i, int n) {
    if (i < 0) i = -i;
    if (i >= n) i = 2 * n - 2 - i;
    return i;
}

// raw row load: A into a[], B into b[] (DIFF only). No subtraction here.
template<int H, int NC, bool DIFF>
__device__ __forceinline__ void load_raw(const float* __restrict__ pa,
                                         const float* __restrict__ pb,
                                         int r, int basec,
                                         float* __restrict__ a,
                                         float* __restrict__ b) {
    const int off = r * H + basec;
    if constexpr (NC == 8) {
        float4 a0 = *(const float4*)(pa + off);
        float4 a1 = *(const float4*)(pa + off + 4);
        a[0]=a0.x; a[1]=a0.y; a[2]=a0.z; a[3]=a0.w;
        a[4]=a1.x; a[5]=a1.y; a[6]=a1.z; a[7]=a1.w;
        if constexpr (DIFF) {
            float4 b0 = *(const float4*)(pb + off);
            float4 b1 = *(const float4*)(pb + off + 4);
            b[0]=b0.x; b[1]=b0.y; b[2]=b0.z; b[3]=b0.w;
            b[4]=b1.x; b[5]=b1.y; b[6]=b1.z; b[7]=b1.w;
        }
    } else if constexpr (NC == 4) {
        float4 a0 = *(const float4*)(pa + off);
        a[0]=a0.x; a[1]=a0.y; a[2]=a0.z; a[3]=a0.w;
        if constexpr (DIFF) {
            float4 b0 = *(const float4*)(pb + off);
            b[0]=b0.x; b[1]=b0.y; b[2]=b0.z; b[3]=b0.w;
        }
    } else {
        float2 a0 = *(const float2*)(pa + off);
        a[0]=a0.x; a[1]=a0.y;
        if constexpr (DIFF) {
            float2 b0 = *(const float2*)(pb + off);
            b[0]=b0.x; b[1]=b0.y;
        }
    }
}

template<int NC, bool DIFF>
__device__ __forceinline__ void materialize(const float* __restrict__ a,
                                            const float* __restrict__ b,
                                            float* __restrict__ c) {
#pragma unroll
    for (int i = 0; i < NC; ++i) c[i] = DIFF ? (a[i] - b[i]) : a[i];
}

// horizontal 5-tap at even cols. c = own NC cols; o = ND outputs.
template<int NC>
__device__ __forceinline__ void hconv(const float* __restrict__ c,
                                      float* __restrict__ o, int lane) {
    constexpr int ND = NC / 2;
    float e[NC + 3];
#pragma unroll
    for (int i = 0; i < NC; ++i) e[i + 2] = c[i];
    const bool l0 = (lane == 0), l63 = (lane == 63);
    { float v = __shfl(e[NC + 1], lane - 1); e[1] = l0 ? e[3] : v; }
    if constexpr (NC >= 4) {
        { float v = __shfl(e[NC], lane - 1); e[0] = l0 ? e[4] : v; }
        { float v = __shfl(e[2], lane + 1); e[NC + 2] = l63 ? e[NC] : v; }
    } else {
        e[0] = __shfl(e[2], l0 ? 1 : lane - 1);
        e[NC + 2] = __shfl(e[2], l63 ? 63 : lane + 1);
    }
#pragma unroll
    for (int j = 0; j < ND; ++j)
        o[j] = KA * e[2*j] + KB * e[2*j+1] + KC * e[2*j+2]
             + KB * e[2*j+3] + KA * e[2*j+4];
}

template<int H, int NC, bool DIFF, int R>
__global__ __launch_bounds__(256, 8) void lap_slide(
        const float* __restrict__ A, const float* __restrict__ B,
        float* __restrict__ down, float* __restrict__ out, float invN) {
    constexpr int Hd = H / 2, ND = NC / 2, SPP = H / R;
    __shared__ float red[4];
    const int tid = threadIdx.x;
    const int lane = tid & 63, wid = tid >> 6;
    const int sid = blockIdx.x * 4 + wid;
    const int bc = sid / SPP;
    const int y0 = (sid % SPP) * R;
    const float* pa = A + (size_t)bc * H * H;
    const float* pb = DIFF ? (B + (size_t)bc * H * H) : nullptr;
    float* pd = down + (size_t)bc * Hd * Hd;
    const int basec = lane * NC;

    float h0[ND], h1[ND], h2[ND], h3[ND], h4[ND];
    float wPrev[NC], pA[NC], pB[NC], pC[NC];  // pending band state
    float nA1[NC], nB1[NC], nA2[NC], nB2[NC]; // prefetch regs
    float c1[NC], c2[NC], t[NC], tb[NC];
#pragma unroll
    for (int i = 0; i < NC; ++i) {
        wPrev[i] = 0.f; pA[i] = 0.f; pB[i] = 0.f; pC[i] = 0.f;
    }
    float acc = 0.f;

    const int d0 = y0 >> 1;
    int dbeg = d0 - 1; if (dbeg < 0) dbeg = 0;
    const int dend = d0 + R / 2;

    // prologue: h-ring rows 2dbeg-2, 2dbeg-1, 2dbeg
    load_raw<H,NC,DIFF>(pa, pb, refl(2*dbeg - 2, H), basec, t, tb);
    materialize<NC,DIFF>(t, tb, c1); hconv<NC>(c1, h0, lane);
    load_raw<H,NC,DIFF>(pa, pb, refl(2*dbeg - 1, H), basec, t, tb);
    materialize<NC,DIFF>(t, tb, c1); hconv<NC>(c1, h1, lane);
    load_raw<H,NC,DIFF>(pa, pb, refl(2*dbeg, H), basec, t, tb);
    materialize<NC,DIFF>(t, tb, c2); hconv<NC>(c2, h2, lane);
    if (d0 == 0) {
        // row 0's pending even state: no W term yet (reflect handled by
        // the ye==0 finalize weights 0.75/0.25).
#pragma unroll
        for (int i = 0; i < NC; ++i) pC[i] = c2[i];
    }
    // prefetch rows for d = dbeg
    load_raw<H,NC,DIFF>(pa, pb, refl(2*dbeg + 1, H), basec, nA1, nB1);
    load_raw<H,NC,DIFF>(pa, pb, refl(2*dbeg + 2, H), basec, nA2, nB2);

    for (int d = dbeg; d <= dend; ++d) {
        // materialize current rows, then immediately issue next-iter loads
        materialize<NC,DIFF>(nA1, nB1, c1);   // raw row 2d+1
        materialize<NC,DIFF>(nA2, nB2, c2);   // raw row 2d+2
        load_raw<H,NC,DIFF>(pa, pb, refl(2*d + 3, H), basec, nA1, nB1);
        load_raw<H,NC,DIFF>(pa, pb, refl(2*d + 4, H), basec, nA2, nB2);

        hconv<NC>(c1, h3, lane);
        hconv<NC>(c2, h4, lane);

        float dn[ND];
#pragma unroll
        for (int j = 0; j < ND; ++j)
            dn[j] = KA*h0[j] + KB*h1[j] + KC*h2[j] + KB*h3[j] + KA*h4[j];

        if (d >= d0 && d < d0 + R/2) {
            const int doff = d * Hd + lane * ND;
            if constexpr (ND == 4) {
                float4 s; s.x=dn[0]; s.y=dn[1]; s.z=dn[2]; s.w=dn[3];
                *(float4*)(pd + doff) = s;
            } else if constexpr (ND == 2) {
                float2 s; s.x=dn[0]; s.y=dn[1];
                *(float2*)(pd + doff) = s;
            } else {
                pd[doff] = dn[0];
            }
        }

        // horizontal-up row W[d] -> wN
        float dm, dp;
        if constexpr (ND >= 2) {
            { float v = __shfl(dn[ND-1], lane - 1); dm = (lane == 0)  ? dn[1]    : v; }
            { float v = __shfl(dn[0],    lane + 1); dp = (lane == 63) ? dn[ND-1] : v; }
        } else {
            dm = __shfl(dn[0], (lane == 0)  ? 1  : lane - 1);
            dp = __shfl(dn[0], (lane == 63) ? 63 : lane + 1);
        }
        float wN[NC];
#pragma unroll
        for (int j = 0; j < ND; ++j) {
            float lf = j ? dn[j-1] : dm;
            float rg = (j + 1 < ND) ? dn[j+1] : dp;
            wN[2*j]     = 0.125f * lf + 0.75f * dn[j] + 0.125f * rg;
            wN[2*j + 1] = 0.5f * (dn[j] + rg);
        }

        // finalize band rows 2d-2 (even, pA) and 2d-1 (odd, pB)
        if (d >= d0 + 1) {
            const int ye = 2 * d - 2;
            if (ye == 0) {
#pragma unroll
                for (int i = 0; i < NC; ++i) {
                    acc += fabsf(pA[i] - (0.75f*wPrev[i] + 0.25f*wN[i]));
                    acc += fabsf(pB[i] - 0.5f*wN[i]);
                }
            } else if (ye == H - 2) {
#pragma unroll
                for (int i = 0; i < NC; ++i) {
                    acc += fabsf(pA[i] - 0.875f*wPrev[i]);
                    acc += fabsf(pB[i] - 0.5f*wPrev[i]);
                }
            } else {
#pragma unroll
                for (int i = 0; i < NC; ++i) {
                    acc += fabsf(pA[i] - (0.75f*wPrev[i] + 0.125f*wN[i]));
                    acc += fabsf(pB[i] - 0.5f*wN[i]);
                }
            }
        }

        // create next pending state + shift rings
#pragma unroll
        for (int i = 0; i < NC; ++i) {
            pA[i] = pC[i];
            pC[i] = c2[i] - 0.125f * wN[i];   // row 2d+2 - 0.125*W[d]
            pB[i] = c1[i] - 0.5f   * wN[i];   // row 2d+1 - 0.5*W[d]
            wPrev[i] = wN[i];
        }
#pragma unroll
        for (int j = 0; j < ND; ++j) { h0[j] = h2[j]; h1[j] = h3[j]; h2[j] = h4[j]; }
    }

#pragma unroll
    for (int off2 = 32; off2 > 0; off2 >>= 1)
        acc += __shfl_down(acc, off2, 64);
    if (lane == 0) red[wid] = acc;
    __syncthreads();
    if (tid == 0)
        atomicAdd(out, (red[0] + red[1] + red[2] + red[3]) * invN);
}

// ---- levels 3 (64->32) and 4 (32->16): one 1024-thr block per plane ----
__global__ __launch_bounds__(1024) void lap_small(
        const float* __restrict__ dsrc, float* __restrict__ out,
        float invN3, float invN4) {
    __shared__ float p[64 * 66];
    __shared__ float hh[64 * 34];
    __shared__ float dd[32 * 34];
    __shared__ float W3[32 * 64];
    __shared__ float h4[32 * 18];
    __shared__ float d4[16 * 18];
    __shared__ float W4[16 * 32];
    __shared__ float red[16];
    const int tid = threadIdx.x;
    const float* src = dsrc + (size_t)blockIdx.x * 4096;
    for (int i = tid; i < 4096; i += 1024)
        p[(i >> 6) * 66 + (i & 63)] = src[i];
    __syncthreads();
    const float k[5] = {KA, KB, KC, KB, KA};
    for (int i = tid; i < 64 * 32; i += 1024) {
        int r = i >> 5, t = i & 31;
        const float* pr = p + r * 66;
        float s = 0.f;
#pragma unroll
        for (int v = 0; v < 5; ++v) s += k[v] * pr[refl(2*t + v - 2, 64)];
        hh[r * 34 + t] = s;
    }
    __syncthreads();
    for (int i = tid; i < 32 * 32; i += 1024) {
        int dy = i >> 5, t = i & 31;
        float s = 0.f;
#pragma unroll
        for (int u = 0; u < 5; ++u) s += k[u] * hh[refl(2*dy + u - 2, 64) * 34 + t];
        dd[dy * 34 + t] = s;
    }
    __syncthreads();
    for (int i = tid; i < 32 * 32; i += 1024) {
        int a = i >> 5, t = i & 31;
        const float* dr = dd + a * 34;
        float dm = dr[t == 0 ? 1 : t - 1];
        float dc = dr[t];
        float dp = dr[t == 31 ? 31 : t + 1];
        W3[a * 64 + 2*t]     = 0.125f * dm + 0.75f * dc + 0.125f * dp;
        W3[a * 64 + 2*t + 1] = 0.5f * (dc + dp);
    }
    __syncthreads();
    float acc3 = 0.f;
    for (int i = tid; i < 4096; i += 1024) {
        int y = i >> 6, x = i & 63;
        float cur = p[y * 66 + x];
        float up;
        if ((y & 1) == 0) {
            int a0 = refl(y - 2, 64) >> 1, a1 = y >> 1, a2 = refl(y + 2, 64) >> 1;
            up = 0.125f*W3[a0*64 + x] + 0.75f*W3[a1*64 + x] + 0.125f*W3[a2*64 + x];
        } else {
            int a0 = (y - 1) >> 1, a1 = refl(y + 1, 64) >> 1;
            up = 0.5f * (W3[a0*64 + x] + W3[a1*64 + x]);
        }
        acc3 += fabsf(cur - up);
    }
    __syncthreads();
    for (int i = tid; i < 32 * 16; i += 1024) {
        int r = i >> 4, t = i & 15;
        const float* pr = dd + r * 34;
        float s = 0.f;
#pragma unroll
        for (int v = 0; v < 5; ++v) s += k[v] * pr[refl(2*t + v - 2, 32)];
        h4[r * 18 + t] = s;
    }
    __syncthreads();
    for (int i = tid; i < 16 * 16; i += 1024) {
        int dy = i >> 4, t = i & 15;
        float s = 0.f;
#pragma unroll
        for (int u = 0; u < 5; ++u) s += k[u] * h4[refl(2*dy + u - 2, 32) * 18 + t];
        d4[dy * 18 + t] = s;
    }
    __syncthreads();
    for (int i = tid; i < 16 * 16; i += 1024) {
        int a = i >> 4, t = i & 15;
        const float* dr = d4 + a * 18;
        float dm = dr[t == 0 ? 1 : t - 1];
        float dc = dr[t];
        float dp = dr[t == 15 ? 15 : t + 1];
        W4[a * 32 + 2*t]     = 0.125f * dm + 0.75f * dc + 0.125f * dp;
        W4[a * 32 + 2*t + 1] = 0.5f * (dc + dp);
    }
    __syncthreads();
    float acc4 = 0.f;
    for (int i = tid; i < 1024; i += 1024) {
        int y = i >> 5, x = i & 31;
        float cur = dd[y * 34 + x];
        float up;
        if ((y & 1) == 0) {
            int a0 = refl(y - 2, 32) >> 1, a1 = y >> 1, a2 = refl(y + 2, 32) >> 1;
            up = 0.125f*W4[a0*32 + x] + 0.75f*W4[a1*32 + x] + 0.125f*W4[a2*32 + x];
        } else {
            int a0 = (y - 1) >> 1, a1 = refl(y + 1, 32) >> 1;
            up = 0.5f * (W4[a0*32 + x] + W4[a1*32 + x]);
        }
        acc4 += fabsf(cur - up);
    }
    float acc = acc3 * invN3 + acc4 * invN4;
#pragma unroll
    for (int off2 = 32; off2 > 0; off2 >>= 1)
        acc += __shfl_down(acc, off2, 64);
    int lane = tid & 63, wid = tid >> 6;
    if (lane == 0) red[wid] = acc;
    __syncthreads();
    if (tid == 0) {
        float s = 0.f;
#pragma unroll
        for (int i = 0; i < 16; ++i) s += red[i];
        atomicAdd(out, s);
    }
}

extern "C" void kernel_launch(void* const* d_in, const int* in_sizes, int n_in,
                              void* d_out, int out_size, void* d_ws, size_t ws_size,
                              hipStream_t stream) {
    const float* in = (const float*)d_in[0];
    const float* tg = (const float*)d_in[1];
    float* out = (float*)d_out;
    float* ws = (float*)d_ws;

    float* down0 = ws;                                   // 96*256*256
    float* down1 = down0 + (size_t)BC * 256 * 256;       // 96*128*128
    float* down2 = down1 + (size_t)BC * 128 * 128;       // 96*64*64

    hipMemsetAsync(out, 0, sizeof(float), stream);

    // level 0: R=8 -> 96*64 strips (6144 waves, 24/CU demand)
    lap_slide<512, 8, true, 8><<<96 * 64 / 4, 256, 0, stream>>>(
        in, tg, down0, out, 1.f / (96.f * 512.f * 512.f));
    // level 1: R=8 -> 96*32 strips (reverted from round-1 R=4)
    lap_slide<256, 4, false, 8><<<96 * 32 / 4, 256, 0, stream>>>(
        down0, nullptr, down1, out, 1.f / (96.f * 256.f * 256.f));
    // level 2: R=4 -> 96*32 strips (reverted from round-1 R=2)
    lap_slide<128, 2, false, 4><<<96 * 32 / 4, 256, 0, stream>>>(
        down1, nullptr, down2, out, 1.f / (96.f * 128.f * 128.f));
    // levels 3+4
    lap_small<<<BC, 1024, 0, stream>>>(
        down2, out, 1.f / (96.f * 64.f * 64.f), 1.f / (96.f * 32.f * 32.f));
}

// Round 3
// 264.324 us; speedup vs baseline: 1.9755x; 1.9755x over previous
//
#include <hip/hip_runtime.h>

// Laplacian pyramid L1 loss, (32,3,512,512) fp32, 5 levels.
// pyramid(in)-pyramid(tg) == pyramid(in-tg) (linearity) -> one pyramid.
// upsample(conv 4K on zero-stuffed) == polyphase on down:
//   even phase taps (.125,.75,.125), odd phase (.5,.5) per axis.
// lap_slide: wave-owned line-sliding pipeline. One wave = one R-row strip.
// Lane owns NC=W/64 cols. Horizontal 5-tap via shuffles, vertical via 5-row
// register ring (h0..h4).
// ROUND-3:
//  * depth-2 ping-pong prefetch: two banks U/V of raw-row landing regs;
//    bank consumed at iter d was loaded at iter d-2 -> load latency overlaps
//    TWO iteration bodies (~600-800cy of ~900cy HBM). Round-0's depth-1
//    overlapped only ~350cy; delivered BW capped at 3.7 TB/s (round-1 proved
//    the fabric gives more when asked: 4.9 TB/s, wasted on halos there).
//  * pending-accumulator band state (verified round-2, absmax 0): band row is
//    born as raw - partial_up, finalized 1-2 iters later. Replaces
//    w-ring+raw-row-ring (48 regs) with {wPrev,pA,pB,pC} (32).
//  * uniform dbeg=d0-1 for ALL strips: reflection symmetry gives
//    W[-1]==W[1] and W[H/2]==W[H/2-1] exactly (symmetric kernel), so the
//    ye==0 / ye==H-2 special finalize branches collapse into the generic
//    path, trip count is uniformly even (R/4+1 double-bodies), and halo
//    shrinks from R+9 to R+7 rows/strip.
//  * NO __launch_bounds__ min-waves (round-2 lesson: forcing 8/SIMD spilled
//    everything -> 1.3GB scratch traffic, 345us). Spill tripwire:
//    WRITE_SIZE must stay ~24.6MB on L0.
// lap_small: levels 3+4, one 1024-thr block per plane.

#define BC 96
#define KA 0.0625f
#define KB 0.25f
#define KC 0.375f

__device__ __forceinline__ int refl(int i, int n) {
    if (i < 0) i = -i;
    if (i >= n) i = 2 * n - 2 - i;
    return i;
}

// raw row load: A into a[], B into b[] (DIFF only). No subtraction here.
template<int H, int NC, bool DIFF>
__device__ __forceinline__ void load_raw(const float* __restrict__ pa,
                                         const float* __restrict__ pb,
                                         int r, int basec,
                                         float* __restrict__ a,
                                         float* __restrict__ b) {
    const int off = r * H + basec;
    if constexpr (NC == 8) {
        float4 a0 = *(const float4*)(pa + off);
        float4 a1 = *(const float4*)(pa + off + 4);
        a[0]=a0.x; a[1]=a0.y; a[2]=a0.z; a[3]=a0.w;
        a[4]=a1.x; a[5]=a1.y; a[6]=a1.z; a[7]=a1.w;
        if constexpr (DIFF) {
            float4 b0 = *(const float4*)(pb + off);
            float4 b1 = *(const float4*)(pb + off + 4);
            b[0]=b0.x; b[1]=b0.y; b[2]=b0.z; b[3]=b0.w;
            b[4]=b1.x; b[5]=b1.y; b[6]=b1.z; b[7]=b1.w;
        }
    } else if constexpr (NC == 4) {
        float4 a0 = *(const float4*)(pa + off);
        a[0]=a0.x; a[1]=a0.y; a[2]=a0.z; a[3]=a0.w;
        if constexpr (DIFF) {
            float4 b0 = *(const float4*)(pb + off);
            b[0]=b0.x; b[1]=b0.y; b[2]=b0.z; b[3]=b0.w;
        }
    } else {
        float2 a0 = *(const float2*)(pa + off);
        a[0]=a0.x; a[1]=a0.y;
        if constexpr (DIFF) {
            float2 b0 = *(const float2*)(pb + off);
            b[0]=b0.x; b[1]=b0.y;
        }
    }
}

template<int NC, bool DIFF>
__device__ __forceinline__ void materialize(const float* __restrict__ a,
                                            const float* __restrict__ b,
                                            float* __restrict__ c) {
#pragma unroll
    for (int i = 0; i < NC; ++i) c[i] = DIFF ? (a[i] - b[i]) : a[i];
}

// horizontal 5-tap at even cols. c = own NC cols; o = ND outputs.
template<int NC>
__device__ __forceinline__ void hconv(const float* __restrict__ c,
                                      float* __restrict__ o, int lane) {
    constexpr int ND = NC / 2;
    float e[NC + 3];
#pragma unroll
    for (int i = 0; i < NC; ++i) e[i + 2] = c[i];
    const bool l0 = (lane == 0), l63 = (lane == 63);
    { float v = __shfl(e[NC + 1], lane - 1); e[1] = l0 ? e[3] : v; }
    if constexpr (NC >= 4) {
        { float v = __shfl(e[NC], lane - 1); e[0] = l0 ? e[4] : v; }
        { float v = __shfl(e[2], lane + 1); e[NC + 2] = l63 ? e[NC] : v; }
    } else {
        e[0] = __shfl(e[2], l0 ? 1 : lane - 1);
        e[NC + 2] = __shfl(e[2], l63 ? 63 : lane + 1);
    }
#pragma unroll
    for (int j = 0; j < ND; ++j)
        o[j] = KA * e[2*j] + KB * e[2*j+1] + KC * e[2*j+2]
             + KB * e[2*j+3] + KA * e[2*j+4];
}

template<int H, int NC, bool DIFF, int R>
__global__ __launch_bounds__(256) void lap_slide(
        const float* __restrict__ A, const float* __restrict__ B,
        float* __restrict__ down, float* __restrict__ out, float invN) {
    constexpr int Hd = H / 2, ND = NC / 2, SPP = H / R;
    constexpr int CNT2 = R / 4 + 1;   // double-bodies per strip
    __shared__ float red[4];
    const int tid = threadIdx.x;
    const int lane = tid & 63, wid = tid >> 6;
    const int sid = blockIdx.x * 4 + wid;
    const int bc = sid / SPP;
    const int y0 = (sid % SPP) * R;
    const float* pa = A + (size_t)bc * H * H;
    const float* pb = DIFF ? (B + (size_t)bc * H * H) : nullptr;
    float* pd = down + (size_t)bc * Hd * Hd;
    const int basec = lane * NC;

    float h0[ND], h1[ND], h2[ND], h3[ND], h4[ND];
    float wPrev[NC], pA[NC], pB[NC], pC[NC];  // pending band state
    float UA1[NC], UA2[NC], VA1[NC], VA2[NC]; // ping-pong prefetch banks
    float UB1[DIFF ? NC : 1], UB2[DIFF ? NC : 1];
    float VB1[DIFF ? NC : 1], VB2[DIFF ? NC : 1];
#pragma unroll
    for (int i = 0; i < NC; ++i) {
        wPrev[i] = 0.f; pA[i] = 0.f; pB[i] = 0.f; pC[i] = 0.f;
    }
    float acc = 0.f;

    const int d0 = y0 >> 1;
    const int db = d0 - 1;   // uniform start (reflection makes W[-1]=W[1])

    // prologue: h-ring rows 2db-2, 2db-1, 2db
    {
        float t[NC], tb[DIFF ? NC : 1], c[NC];
        load_raw<H,NC,DIFF>(pa, pb, refl(2*db - 2, H), basec, t, tb);
        materialize<NC,DIFF>(t, tb, c); hconv<NC>(c, h0, lane);
        load_raw<H,NC,DIFF>(pa, pb, refl(2*db - 1, H), basec, t, tb);
        materialize<NC,DIFF>(t, tb, c); hconv<NC>(c, h1, lane);
        load_raw<H,NC,DIFF>(pa, pb, refl(2*db, H), basec, t, tb);
        materialize<NC,DIFF>(t, tb, c); hconv<NC>(c, h2, lane);
    }
    // fill both banks: U <- rows for iter db, V <- rows for iter db+1
    load_raw<H,NC,DIFF>(pa, pb, refl(2*db + 1, H), basec, UA1, UB1);
    load_raw<H,NC,DIFF>(pa, pb, refl(2*db + 2, H), basec, UA2, UB2);
    load_raw<H,NC,DIFF>(pa, pb, refl(2*db + 3, H), basec, VA1, VB1);
    load_raw<H,NC,DIFF>(pa, pb, refl(2*db + 4, H), basec, VA2, VB2);

    // one iteration body. Bank consumed here was loaded 2 bodies ago.
    auto body = [&](int d, float* A1, float* A2, float* B1, float* B2,
                    bool doFin, bool doStore, bool doIssue) {
        float c1[NC], c2[NC];
        materialize<NC,DIFF>(A1, B1, c1);   // raw row 2d+1
        materialize<NC,DIFF>(A2, B2, c2);   // raw row 2d+2
        if (doIssue) {                      // refill for iter d+2
            load_raw<H,NC,DIFF>(pa, pb, refl(2*d + 5, H), basec, A1, B1);
            load_raw<H,NC,DIFF>(pa, pb, refl(2*d + 6, H), basec, A2, B2);
        }
        hconv<NC>(c1, h3, lane);
        hconv<NC>(c2, h4, lane);

        float dn[ND];
#pragma unroll
        for (int j = 0; j < ND; ++j)
            dn[j] = KA*h0[j] + KB*h1[j] + KC*h2[j] + KB*h3[j] + KA*h4[j];

        if (doStore) {
            const int doff = d * Hd + lane * ND;
            if constexpr (ND == 4) {
                float4 s; s.x=dn[0]; s.y=dn[1]; s.z=dn[2]; s.w=dn[3];
                *(float4*)(pd + doff) = s;
            } else if constexpr (ND == 2) {
                float2 s; s.x=dn[0]; s.y=dn[1];
                *(float2*)(pd + doff) = s;
            } else {
                pd[doff] = dn[0];
            }
        }

        // horizontal-up row W[d] -> wN
        float dm, dp;
        if constexpr (ND >= 2) {
            { float v = __shfl(dn[ND-1], lane - 1); dm = (lane == 0)  ? dn[1]    : v; }
            { float v = __shfl(dn[0],    lane + 1); dp = (lane == 63) ? dn[ND-1] : v; }
        } else {
            dm = __shfl(dn[0], (lane == 0)  ? 1  : lane - 1);
            dp = __shfl(dn[0], (lane == 63) ? 63 : lane + 1);
        }
        float wN[NC];
#pragma unroll
        for (int j = 0; j < ND; ++j) {
            float lf = j ? dn[j-1] : dm;
            float rg = (j + 1 < ND) ? dn[j+1] : dp;
            wN[2*j]     = 0.125f * lf + 0.75f * dn[j] + 0.125f * rg;
            wN[2*j + 1] = 0.5f * (dn[j] + rg);
        }

        // finalize band rows 2d-2 (even, pA) and 2d-1 (odd, pB).
        // Generic path only: boundary cases collapsed by W[-1]=W[1],
        // W[H/2]=W[H/2-1] (reflection symmetry of the symmetric kernel).
        if (doFin) {
#pragma unroll
            for (int i = 0; i < NC; ++i) {
                acc += fabsf(pA[i] - (0.75f*wPrev[i] + 0.125f*wN[i]));
                acc += fabsf(pB[i] - 0.5f*wN[i]);
            }
        }

        // create next pending state + shift rings
#pragma unroll
        for (int i = 0; i < NC; ++i) {
            pA[i] = pC[i];
            pC[i] = c2[i] - 0.125f * wN[i];   // even row 2d+2 - 0.125*W[d]
            pB[i] = c1[i] - 0.5f   * wN[i];   // odd  row 2d+1 - 0.5*W[d]
            wPrev[i] = wN[i];
        }
#pragma unroll
        for (int j = 0; j < ND; ++j) { h0[j] = h2[j]; h1[j] = h3[j]; h2[j] = h4[j]; }
    };

#pragma unroll
    for (int i = 0; i < CNT2; ++i) {
        const bool fin = (i >= 1);
        const bool iss = (i < CNT2 - 1);
        // U-body: d = db+2i. stores rows d0+1, d0+3, ... (i>=1)
        body(db + 2*i,     UA1, UA2, UB1, UB2, fin, i >= 1,       iss);
        // V-body: d = db+2i+1. stores rows d0, d0+2, ... (i<CNT2-1)
        body(db + 2*i + 1, VA1, VA2, VB1, VB2, fin, i < CNT2 - 1, iss);
    }

#pragma unroll
    for (int off2 = 32; off2 > 0; off2 >>= 1)
        acc += __shfl_down(acc, off2, 64);
    if (lane == 0) red[wid] = acc;
    __syncthreads();
    if (tid == 0)
        atomicAdd(out, (red[0] + red[1] + red[2] + red[3]) * invN);
}

// ---- levels 3 (64->32) and 4 (32->16): one 1024-thr block per plane ----
__global__ __launch_bounds__(1024) void lap_small(
        const float* __restrict__ dsrc, float* __restrict__ out,
        float invN3, float invN4) {
    __shared__ float p[64 * 66];
    __shared__ float hh[64 * 34];
    __shared__ float dd[32 * 34];
    __shared__ float W3[32 * 64];
    __shared__ float h4[32 * 18];
    __shared__ float d4[16 * 18];
    __shared__ float W4[16 * 32];
    __shared__ float red[16];
    const int tid = threadIdx.x;
    const float* src = dsrc + (size_t)blockIdx.x * 4096;
    for (int i = tid; i < 4096; i += 1024)
        p[(i >> 6) * 66 + (i & 63)] = src[i];
    __syncthreads();
    const float k[5] = {KA, KB, KC, KB, KA};
    for (int i = tid; i < 64 * 32; i += 1024) {
        int r = i >> 5, t = i & 31;
        const float* pr = p + r * 66;
        float s = 0.f;
#pragma unroll
        for (int v = 0; v < 5; ++v) s += k[v] * pr[refl(2*t + v - 2, 64)];
        hh[r * 34 + t] = s;
    }
    __syncthreads();
    for (int i = tid; i < 32 * 32; i += 1024) {
        int dy = i >> 5, t = i & 31;
        float s = 0.f;
#pragma unroll
        for (int u = 0; u < 5; ++u) s += k[u] * hh[refl(2*dy + u - 2, 64) * 34 + t];
        dd[dy * 34 + t] = s;
    }
    __syncthreads();
    for (int i = tid; i < 32 * 32; i += 1024) {
        int a = i >> 5, t = i & 31;
        const float* dr = dd + a * 34;
        float dm = dr[t == 0 ? 1 : t - 1];
        float dc = dr[t];
        float dp = dr[t == 31 ? 31 : t + 1];
        W3[a * 64 + 2*t]     = 0.125f * dm + 0.75f * dc + 0.125f * dp;
        W3[a * 64 + 2*t + 1] = 0.5f * (dc + dp);
    }
    __syncthreads();
    float acc3 = 0.f;
    for (int i = tid; i < 4096; i += 1024) {
        int y = i >> 6, x = i & 63;
        float cur = p[y * 66 + x];
        float up;
        if ((y & 1) == 0) {
            int a0 = refl(y - 2, 64) >> 1, a1 = y >> 1, a2 = refl(y + 2, 64) >> 1;
            up = 0.125f*W3[a0*64 + x] + 0.75f*W3[a1*64 + x] + 0.125f*W3[a2*64 + x];
        } else {
            int a0 = (y - 1) >> 1, a1 = refl(y + 1, 64) >> 1;
            up = 0.5f * (W3[a0*64 + x] + W3[a1*64 + x]);
        }
        acc3 += fabsf(cur - up);
    }
    __syncthreads();
    for (int i = tid; i < 32 * 16; i += 1024) {
        int r = i >> 4, t = i & 15;
        const float* pr = dd + r * 34;
        float s = 0.f;
#pragma unroll
        for (int v = 0; v < 5; ++v) s += k[v] * pr[refl(2*t + v - 2, 32)];
        h4[r * 18 + t] = s;
    }
    __syncthreads();
    for (int i = tid; i < 16 * 16; i += 1024) {
        int dy = i >> 4, t = i & 15;
        float s = 0.f;
#pragma unroll
        for (int u = 0; u < 5; ++u) s += k[u] * h4[refl(2*dy + u - 2, 32) * 18 + t];
        d4[dy * 18 + t] = s;
    }
    __syncthreads();
    for (int i = tid; i < 16 * 16; i += 1024) {
        int a = i >> 4, t = i & 15;
        const float* dr = d4 + a * 18;
        float dm = dr[t == 0 ? 1 : t - 1];
        float dc = dr[t];
        float dp = dr[t == 15 ? 15 : t + 1];
        W4[a * 32 + 2*t]     = 0.125f * dm + 0.75f * dc + 0.125f * dp;
        W4[a * 32 + 2*t + 1] = 0.5f * (dc + dp);
    }
    __syncthreads();
    float acc4 = 0.f;
    for (int i = tid; i < 1024; i += 1024) {
        int y = i >> 5, x = i & 31;
        float cur = dd[y * 34 + x];
        float up;
        if ((y & 1) == 0) {
            int a0 = refl(y - 2, 32) >> 1, a1 = y >> 1, a2 = refl(y + 2, 32) >> 1;
            up = 0.125f*W4[a0*32 + x] + 0.75f*W4[a1*32 + x] + 0.125f*W4[a2*32 + x];
        } else {
            int a0 = (y - 1) >> 1, a1 = refl(y + 1, 32) >> 1;
            up = 0.5f * (W4[a0*32 + x] + W4[a1*32 + x]);
        }
        acc4 += fabsf(cur - up);
    }
    float acc = acc3 * invN3 + acc4 * invN4;
#pragma unroll
    for (int off2 = 32; off2 > 0; off2 >>= 1)
        acc += __shfl_down(acc, off2, 64);
    int lane = tid & 63, wid = tid >> 6;
    if (lane == 0) red[wid] = acc;
    __syncthreads();
    if (tid == 0) {
        float s = 0.f;
#pragma unroll
        for (int i = 0; i < 16; ++i) s += red[i];
        atomicAdd(out, s);
    }
}

extern "C" void kernel_launch(void* const* d_in, const int* in_sizes, int n_in,
                              void* d_out, int out_size, void* d_ws, size_t ws_size,
                              hipStream_t stream) {
    const float* in = (const float*)d_in[0];
    const float* tg = (const float*)d_in[1];
    float* out = (float*)d_out;
    float* ws = (float*)d_ws;

    float* down0 = ws;                                   // 96*256*256
    float* down1 = down0 + (size_t)BC * 256 * 256;       // 96*128*128
    float* down2 = down1 + (size_t)BC * 128 * 128;       // 96*64*64

    hipMemsetAsync(out, 0, sizeof(float), stream);

    // level 0: R=16 -> 96*32 strips (round-0 grid), depth-2 prefetch
    lap_slide<512, 8, true, 16><<<96 * 32 / 4, 256, 0, stream>>>(
        in, tg, down0, out, 1.f / (96.f * 512.f * 512.f));
    // level 1: R=8 -> 96*32 strips
    lap_slide<256, 4, false, 8><<<96 * 32 / 4, 256, 0, stream>>>(
        down0, nullptr, down1, out, 1.f / (96.f * 256.f * 256.f));
    // level 2: R=4 -> 96*32 strips
    lap_slide<128, 2, false, 4><<<96 * 32 / 4, 256, 0, stream>>>(
        down1, nullptr, down2, out, 1.f / (96.f * 128.f * 128.f));
    // levels 3+4
    lap_small<<<BC, 1024, 0, stream>>>(
        down2, out, 1.f / (96.f * 64.f * 64.f), 1.f / (96.f * 32.f * 32.f));
}

// Round 4
// 244.068 us; speedup vs baseline: 2.1395x; 1.0830x over previous
//
#include <hip/hip_runtime.h>

// Laplacian pyramid L1 loss, (32,3,512,512) fp32, 5 levels.
// pyramid(in)-pyramid(tg) == pyramid(in-tg) (linearity) -> one pyramid.
// upsample(conv 4K on zero-stuffed) == polyphase on down:
//   even phase taps (.125,.75,.125), odd phase (.5,.5) per axis.
//
// slide_strip: wave-owned line-sliding pipeline (verified R3, absmax 0):
//   depth-2 ping-pong prefetch banks, pending-accumulator band state,
//   uniform db=d0-1 start (reflection symmetry W[-1]=W[1], W[H/2]=W[H/2-1]
//   collapses boundary finalize branches). Parameterized on src/dst row
//   stride so the same body runs global->global (L0) and global/LDS->LDS
//   (fused tail).
//
// ROUND-4: tail fusion. Timeline analysis: L0 ~90us but TOTAL ~264us; the
// tail (L1+L2+lap_small+4 launch gaps) ~174us across rounds 0/2/3 -- all
// tiny-data latency/launch-bound kernels. lap_rest fuses levels 1-4 into
// one kernel, one block per plane (96 x 1024thr = 16 waves):
//   L1: slide, 16 waves x 16-row strips, global down0 -> LDS down1[128*128]
//   L2: slide, 16 waves x 8-row strips, LDS down1 -> LDS p[64*66] (padded)
//   L3/L4: existing lap_small code verbatim on p.
// LDS ~107 KB static (gfx950 LDS=160KB; 128KB static proven in learn_hip).
// Kills down1/down2 global round-trips + 2 launch gaps (5 kernels -> 3).
// L0 unchanged from R3 (local optimum ~90us; FETCH 127MB, no spill).
// Spill tripwire: lap_rest WRITE_SIZE ~= 0.

#define BC 96
#define KA 0.0625f
#define KB 0.25f
#define KC 0.375f

__device__ __forceinline__ int refl(int i, int n) {
    if (i < 0) i = -i;
    if (i >= n) i = 2 * n - 2 - i;
    return i;
}

// raw row load at row r: A into a[], B into b[] (DIFF only). SS = src row stride.
template<int SS, int NC, bool DIFF>
__device__ __forceinline__ void load_raw(const float* __restrict__ pa,
                                         const float* __restrict__ pb,
                                         int r, int basec,
                                         float* __restrict__ a,
                                         float* __restrict__ b) {
    const int off = r * SS + basec;
    if constexpr (NC == 8) {
        float4 a0 = *(const float4*)(pa + off);
        float4 a1 = *(const float4*)(pa + off + 4);
        a[0]=a0.x; a[1]=a0.y; a[2]=a0.z; a[3]=a0.w;
        a[4]=a1.x; a[5]=a1.y; a[6]=a1.z; a[7]=a1.w;
        if constexpr (DIFF) {
            float4 b0 = *(const float4*)(pb + off);
            float4 b1 = *(const float4*)(pb + off + 4);
            b[0]=b0.x; b[1]=b0.y; b[2]=b0.z; b[3]=b0.w;
            b[4]=b1.x; b[5]=b1.y; b[6]=b1.z; b[7]=b1.w;
        }
    } else if constexpr (NC == 4) {
        float4 a0 = *(const float4*)(pa + off);
        a[0]=a0.x; a[1]=a0.y; a[2]=a0.z; a[3]=a0.w;
        if constexpr (DIFF) {
            float4 b0 = *(const float4*)(pb + off);
            b[0]=b0.x; b[1]=b0.y; b[2]=b0.z; b[3]=b0.w;
        }
    } else {
        float2 a0 = *(const float2*)(pa + off);
        a[0]=a0.x; a[1]=a0.y;
        if constexpr (DIFF) {
            float2 b0 = *(const float2*)(pb + off);
            b[0]=b0.x; b[1]=b0.y;
        }
    }
}

template<int NC, bool DIFF>
__device__ __forceinline__ void materialize(const float* __restrict__ a,
                                            const float* __restrict__ b,
                                            float* __restrict__ c) {
#pragma unroll
    for (int i = 0; i < NC; ++i) c[i] = DIFF ? (a[i] - b[i]) : a[i];
}

// horizontal 5-tap at even cols. c = own NC cols; o = ND outputs.
template<int NC>
__device__ __forceinline__ void hconv(const float* __restrict__ c,
                                      float* __restrict__ o, int lane) {
    constexpr int ND = NC / 2;
    float e[NC + 3];
#pragma unroll
    for (int i = 0; i < NC; ++i) e[i + 2] = c[i];
    const bool l0 = (lane == 0), l63 = (lane == 63);
    { float v = __shfl(e[NC + 1], lane - 1); e[1] = l0 ? e[3] : v; }
    if constexpr (NC >= 4) {
        { float v = __shfl(e[NC], lane - 1); e[0] = l0 ? e[4] : v; }
        { float v = __shfl(e[2], lane + 1); e[NC + 2] = l63 ? e[NC] : v; }
    } else {
        e[0] = __shfl(e[2], l0 ? 1 : lane - 1);
        e[NC + 2] = __shfl(e[2], l63 ? 63 : lane + 1);
    }
#pragma unroll
    for (int j = 0; j < ND; ++j)
        o[j] = KA * e[2*j] + KB * e[2*j+1] + KC * e[2*j+2]
             + KB * e[2*j+3] + KA * e[2*j+4];
}

// One R-row strip of one level: band L1-sum returned; down rows written to
// pd (row stride DS). Verified algebra (R3, absmax 0).
template<int H, int NC, int R, int SS, int DS, bool DIFF>
__device__ __forceinline__ float slide_strip(
        const float* __restrict__ pa, const float* __restrict__ pb,
        float* __restrict__ pd, int lane, int y0) {
    constexpr int ND = NC / 2;
    constexpr int CNT2 = R / 4 + 1;   // double-bodies per strip
    const int basec = lane * NC;

    float h0[ND], h1[ND], h2[ND], h3[ND], h4[ND];
    float wPrev[NC], pA[NC], pB[NC], pC[NC];  // pending band state
    float UA1[NC], UA2[NC], VA1[NC], VA2[NC]; // ping-pong prefetch banks
    float UB1[DIFF ? NC : 1], UB2[DIFF ? NC : 1];
    float VB1[DIFF ? NC : 1], VB2[DIFF ? NC : 1];
#pragma unroll
    for (int i = 0; i < NC; ++i) {
        wPrev[i] = 0.f; pA[i] = 0.f; pB[i] = 0.f; pC[i] = 0.f;
    }
    float acc = 0.f;

    const int d0 = y0 >> 1;
    const int db = d0 - 1;   // uniform start (reflection makes W[-1]=W[1])

    // prologue: h-ring rows 2db-2, 2db-1, 2db
    {
        float t[NC], tb[DIFF ? NC : 1], c[NC];
        load_raw<SS,NC,DIFF>(pa, pb, refl(2*db - 2, H), basec, t, tb);
        materialize<NC,DIFF>(t, tb, c); hconv<NC>(c, h0, lane);
        load_raw<SS,NC,DIFF>(pa, pb, refl(2*db - 1, H), basec, t, tb);
        materialize<NC,DIFF>(t, tb, c); hconv<NC>(c, h1, lane);
        load_raw<SS,NC,DIFF>(pa, pb, refl(2*db, H), basec, t, tb);
        materialize<NC,DIFF>(t, tb, c); hconv<NC>(c, h2, lane);
    }
    // fill both banks: U <- rows for iter db, V <- rows for iter db+1
    load_raw<SS,NC,DIFF>(pa, pb, refl(2*db + 1, H), basec, UA1, UB1);
    load_raw<SS,NC,DIFF>(pa, pb, refl(2*db + 2, H), basec, UA2, UB2);
    load_raw<SS,NC,DIFF>(pa, pb, refl(2*db + 3, H), basec, VA1, VB1);
    load_raw<SS,NC,DIFF>(pa, pb, refl(2*db + 4, H), basec, VA2, VB2);

    // one iteration body. Bank consumed here was loaded 2 bodies ago.
    auto body = [&](int d, float* A1, float* A2, float* B1, float* B2,
                    bool doFin, bool doStore, bool doIssue) {
        float c1[NC], c2[NC];
        materialize<NC,DIFF>(A1, B1, c1);   // raw row 2d+1
        materialize<NC,DIFF>(A2, B2, c2);   // raw row 2d+2
        if (doIssue) {                      // refill for iter d+2
            load_raw<SS,NC,DIFF>(pa, pb, refl(2*d + 5, H), basec, A1, B1);
            load_raw<SS,NC,DIFF>(pa, pb, refl(2*d + 6, H), basec, A2, B2);
        }
        hconv<NC>(c1, h3, lane);
        hconv<NC>(c2, h4, lane);

        float dn[ND];
#pragma unroll
        for (int j = 0; j < ND; ++j)
            dn[j] = KA*h0[j] + KB*h1[j] + KC*h2[j] + KB*h3[j] + KA*h4[j];

        if (doStore) {
            const int doff = d * DS + lane * ND;
            if constexpr (ND == 4) {
                float4 s; s.x=dn[0]; s.y=dn[1]; s.z=dn[2]; s.w=dn[3];
                *(float4*)(pd + doff) = s;
            } else if constexpr (ND == 2) {
                float2 s; s.x=dn[0]; s.y=dn[1];
                *(float2*)(pd + doff) = s;
            } else {
                pd[doff] = dn[0];
            }
        }

        // horizontal-up row W[d] -> wN
        float dm, dp;
        if constexpr (ND >= 2) {
            { float v = __shfl(dn[ND-1], lane - 1); dm = (lane == 0)  ? dn[1]    : v; }
            { float v = __shfl(dn[0],    lane + 1); dp = (lane == 63) ? dn[ND-1] : v; }
        } else {
            dm = __shfl(dn[0], (lane == 0)  ? 1  : lane - 1);
            dp = __shfl(dn[0], (lane == 63) ? 63 : lane + 1);
        }
        float wN[NC];
#pragma unroll
        for (int j = 0; j < ND; ++j) {
            float lf = j ? dn[j-1] : dm;
            float rg = (j + 1 < ND) ? dn[j+1] : dp;
            wN[2*j]     = 0.125f * lf + 0.75f * dn[j] + 0.125f * rg;
            wN[2*j + 1] = 0.5f * (dn[j] + rg);
        }

        // finalize band rows 2d-2 (even, pA) and 2d-1 (odd, pB).
        if (doFin) {
#pragma unroll
            for (int i = 0; i < NC; ++i) {
                acc += fabsf(pA[i] - (0.75f*wPrev[i] + 0.125f*wN[i]));
                acc += fabsf(pB[i] - 0.5f*wN[i]);
            }
        }

        // create next pending state + shift rings
#pragma unroll
        for (int i = 0; i < NC; ++i) {
            pA[i] = pC[i];
            pC[i] = c2[i] - 0.125f * wN[i];   // even row 2d+2 - 0.125*W[d]
            pB[i] = c1[i] - 0.5f   * wN[i];   // odd  row 2d+1 - 0.5*W[d]
            wPrev[i] = wN[i];
        }
#pragma unroll
        for (int j = 0; j < ND; ++j) { h0[j] = h2[j]; h1[j] = h3[j]; h2[j] = h4[j]; }
    };

#pragma unroll
    for (int i = 0; i < CNT2; ++i) {
        const bool fin = (i >= 1);
        const bool iss = (i < CNT2 - 1);
        body(db + 2*i,     UA1, UA2, UB1, UB2, fin, i >= 1,       iss);
        body(db + 2*i + 1, VA1, VA2, VB1, VB2, fin, i < CNT2 - 1, iss);
    }
    return acc;
}

// ---- level 0: global->global, 4 waves/block, one strip per wave ----
template<int H, int NC, bool DIFF, int R>
__global__ __launch_bounds__(256) void lap_slide(
        const float* __restrict__ A, const float* __restrict__ B,
        float* __restrict__ down, float* __restrict__ out, float invN) {
    constexpr int Hd = H / 2, SPP = H / R;
    __shared__ float red[4];
    const int tid = threadIdx.x;
    const int lane = tid & 63, wid = tid >> 6;
    const int sid = blockIdx.x * 4 + wid;
    const int bc = sid / SPP;
    const int y0 = (sid % SPP) * R;
    const float* pa = A + (size_t)bc * H * H;
    const float* pb = DIFF ? (B + (size_t)bc * H * H) : nullptr;
    float* pd = down + (size_t)bc * Hd * Hd;

    float acc = slide_strip<H, NC, R, H, Hd, DIFF>(pa, pb, pd, lane, y0);

#pragma unroll
    for (int off2 = 32; off2 > 0; off2 >>= 1)
        acc += __shfl_down(acc, off2, 64);
    if (lane == 0) red[wid] = acc;
    __syncthreads();
    if (tid == 0)
        atomicAdd(out, (red[0] + red[1] + red[2] + red[3]) * invN);
}

// ---- levels 1..4 fused: one 1024-thr block per plane ----
__global__ __launch_bounds__(1024) void lap_rest(
        const float* __restrict__ down0, float* __restrict__ out,
        float invN1, float invN2, float invN3, float invN4) {
    __shared__ float d1[128 * 128];   // down1 (level-1 output)
    __shared__ float p[64 * 66];      // down2, padded (lap_small layout)
    __shared__ float hh[64 * 34];
    __shared__ float dd[32 * 34];
    __shared__ float W3[32 * 64];
    __shared__ float h4[32 * 18];
    __shared__ float d4[16 * 18];
    __shared__ float W4[16 * 32];
    __shared__ float red[16];
    const int tid = threadIdx.x;
    const int lane = tid & 63, wid = tid >> 6;   // 16 waves
    const float* src = down0 + (size_t)blockIdx.x * 65536;

    // L1: H=256, NC=4, R=16 strips; src global (stride 256) -> d1 (stride 128)
    float acc = invN1 *
        slide_strip<256, 4, 16, 256, 128, false>(src, nullptr, d1, lane, wid * 16);
    __syncthreads();
    // L2: H=128, NC=2, R=8 strips; src d1 (stride 128) -> p (stride 66, ND=1)
    acc += invN2 *
        slide_strip<128, 2, 8, 128, 66, false>(d1, nullptr, p, lane, wid * 8);
    __syncthreads();

    // L3/L4: existing verified lap_small code on p
    const float k[5] = {KA, KB, KC, KB, KA};
    for (int i = tid; i < 64 * 32; i += 1024) {
        int r = i >> 5, t = i & 31;
        const float* pr = p + r * 66;
        float s = 0.f;
#pragma unroll
        for (int v = 0; v < 5; ++v) s += k[v] * pr[refl(2*t + v - 2, 64)];
        hh[r * 34 + t] = s;
    }
    __syncthreads();
    for (int i = tid; i < 32 * 32; i += 1024) {
        int dy = i >> 5, t = i & 31;
        float s = 0.f;
#pragma unroll
        for (int u = 0; u < 5; ++u) s += k[u] * hh[refl(2*dy + u - 2, 64) * 34 + t];
        dd[dy * 34 + t] = s;
    }
    __syncthreads();
    for (int i = tid; i < 32 * 32; i += 1024) {
        int a = i >> 5, t = i & 31;
        const float* dr = dd + a * 34;
        float dm = dr[t == 0 ? 1 : t - 1];
        float dc = dr[t];
        float dp = dr[t == 31 ? 31 : t + 1];
        W3[a * 64 + 2*t]     = 0.125f * dm + 0.75f * dc + 0.125f * dp;
        W3[a * 64 + 2*t + 1] = 0.5f * (dc + dp);
    }
    __syncthreads();
    float acc3 = 0.f;
    for (int i = tid; i < 4096; i += 1024) {
        int y = i >> 6, x = i & 63;
        float cur = p[y * 66 + x];
        float up;
        if ((y & 1) == 0) {
            int a0 = refl(y - 2, 64) >> 1, a1 = y >> 1, a2 = refl(y + 2, 64) >> 1;
            up = 0.125f*W3[a0*64 + x] + 0.75f*W3[a1*64 + x] + 0.125f*W3[a2*64 + x];
        } else {
            int a0 = (y - 1) >> 1, a1 = refl(y + 1, 64) >> 1;
            up = 0.5f * (W3[a0*64 + x] + W3[a1*64 + x]);
        }
        acc3 += fabsf(cur - up);
    }
    __syncthreads();
    for (int i = tid; i < 32 * 16; i += 1024) {
        int r = i >> 4, t = i & 15;
        const float* pr = dd + r * 34;
        float s = 0.f;
#pragma unroll
        for (int v = 0; v < 5; ++v) s += k[v] * pr[refl(2*t + v - 2, 32)];
        h4[r * 18 + t] = s;
    }
    __syncthreads();
    for (int i = tid; i < 16 * 16; i += 1024) {
        int dy = i >> 4, t = i & 15;
        float s = 0.f;
#pragma unroll
        for (int u = 0; u < 5; ++u) s += k[u] * h4[refl(2*dy + u - 2, 32) * 18 + t];
        d4[dy * 18 + t] = s;
    }
    __syncthreads();
    for (int i = tid; i < 16 * 16; i += 1024) {
        int a = i >> 4, t = i & 15;
        const float* dr = d4 + a * 18;
        float dm = dr[t == 0 ? 1 : t - 1];
        float dc = dr[t];
        float dp = dr[t == 15 ? 15 : t + 1];
        W4[a * 32 + 2*t]     = 0.125f * dm + 0.75f * dc + 0.125f * dp;
        W4[a * 32 + 2*t + 1] = 0.5f * (dc + dp);
    }
    __syncthreads();
    float acc4 = 0.f;
    for (int i = tid; i < 1024; i += 1024) {
        int y = i >> 5, x = i & 31;
        float cur = dd[y * 34 + x];
        float up;
        if ((y & 1) == 0) {
            int a0 = refl(y - 2, 32) >> 1, a1 = y >> 1, a2 = refl(y + 2, 32) >> 1;
            up = 0.125f*W4[a0*32 + x] + 0.75f*W4[a1*32 + x] + 0.125f*W4[a2*32 + x];
        } else {
            int a0 = (y - 1) >> 1, a1 = refl(y + 1, 32) >> 1;
            up = 0.5f * (W4[a0*32 + x] + W4[a1*32 + x]);
        }
        acc4 += fabsf(cur - up);
    }
    acc += acc3 * invN3 + acc4 * invN4;

#pragma unroll
    for (int off2 = 32; off2 > 0; off2 >>= 1)
        acc += __shfl_down(acc, off2, 64);
    if (lane == 0) red[wid] = acc;
    __syncthreads();
    if (tid == 0) {
        float s = 0.f;
#pragma unroll
        for (int i = 0; i < 16; ++i) s += red[i];
        atomicAdd(out, s);
    }
}

extern "C" void kernel_launch(void* const* d_in, const int* in_sizes, int n_in,
                              void* d_out, int out_size, void* d_ws, size_t ws_size,
                              hipStream_t stream) {
    const float* in = (const float*)d_in[0];
    const float* tg = (const float*)d_in[1];
    float* out = (float*)d_out;
    float* ws = (float*)d_ws;

    float* down0 = ws;   // 96*256*256 floats

    hipMemsetAsync(out, 0, sizeof(float), stream);

    // level 0: R=16 -> 96*32 strips, depth-2 prefetch (unchanged from R3)
    lap_slide<512, 8, true, 16><<<96 * 32 / 4, 256, 0, stream>>>(
        in, tg, down0, out, 1.f / (96.f * 512.f * 512.f));
    // levels 1-4 fused: one block per plane
    lap_rest<<<BC, 1024, 0, stream>>>(
        down0, out,
        1.f / (96.f * 256.f * 256.f), 1.f / (96.f * 128.f * 128.f),
        1.f / (96.f * 64.f * 64.f),  1.f / (96.f * 32.f * 32.f));
}

// Round 6
// 243.711 us; speedup vs baseline: 2.1426x; 1.0015x over previous
//
#include <hip/hip_runtime.h>

// Laplacian pyramid L1 loss, (32,3,512,512) fp32, 5 levels.
// pyramid(in)-pyramid(tg) == pyramid(in-tg) (linearity) -> one pyramid.
// upsample(conv 4K on zero-stuffed) == polyphase on down:
//   even phase taps (.125,.75,.125), odd phase (.5,.5) per axis.
//
// slide_strip: wave-owned line-sliding pipeline (verified R3/R4, absmax 0):
//   pending-accumulator band state, uniform db=d0-1 start (reflection
//   symmetry W[-1]=W[1], W[H/2]=W[H/2-1] collapses boundary branches).
//   PD template param = prefetch depth:
//     PD=2: ping-pong U/V banks, loads issued 2 bodies ahead (for HBM ~900cy)
//     PD=1: single U bank, loads issued 1 body ahead (for L2/LDS ~120-200cy)
//
// ROUND-6 = ROUND-5 resubmitted verbatim (round-5 bench was an infra
// failure: "container failed twice", no counters -- no information to
// update on; stacking a second change would make the next result
// unattributable).
// ROUND-5 rationale: lap_rest spill fix. R4 fused the tail but only saved
// 20us; by subtraction lap_rest ran ~80-90us vs ~20us expected. Suspect:
// 1024-thr launch_bounds caps VGPR at 128 (512/4 waves per SIMD), and the
// NC=4 depth-2 slide_strip (~156 VGPR at NC=8) + lap_small arrays exceeds
// it -> scratch spill (round-2 failure mode; tripwire wasn't visible
// because lap_rest missed the counter top-5). Depth-2 is useless in the
// tail anyway (src is L2/L3/LDS-resident, not 900cy HBM). Tail now PD=1;
// L0 keeps PD=2 (byte-identical codegen = control).
// Spill check if lap_rest surfaces: WRITE_SIZE ~= 0.
// L0 unchanged from R3 (~90us local optimum; FETCH ~126MB).

#define BC 96
#define KA 0.0625f
#define KB 0.25f
#define KC 0.375f

__device__ __forceinline__ int refl(int i, int n) {
    if (i < 0) i = -i;
    if (i >= n) i = 2 * n - 2 - i;
    return i;
}

// raw row load at row r: A into a[], B into b[] (DIFF only). SS = src row stride.
template<int SS, int NC, bool DIFF>
__device__ __forceinline__ void load_raw(const float* __restrict__ pa,
                                         const float* __restrict__ pb,
                                         int r, int basec,
                                         float* __restrict__ a,
                                         float* __restrict__ b) {
    const int off = r * SS + basec;
    if constexpr (NC == 8) {
        float4 a0 = *(const float4*)(pa + off);
        float4 a1 = *(const float4*)(pa + off + 4);
        a[0]=a0.x; a[1]=a0.y; a[2]=a0.z; a[3]=a0.w;
        a[4]=a1.x; a[5]=a1.y; a[6]=a1.z; a[7]=a1.w;
        if constexpr (DIFF) {
            float4 b0 = *(const float4*)(pb + off);
            float4 b1 = *(const float4*)(pb + off + 4);
            b[0]=b0.x; b[1]=b0.y; b[2]=b0.z; b[3]=b0.w;
            b[4]=b1.x; b[5]=b1.y; b[6]=b1.z; b[7]=b1.w;
        }
    } else if constexpr (NC == 4) {
        float4 a0 = *(const float4*)(pa + off);
        a[0]=a0.x; a[1]=a0.y; a[2]=a0.z; a[3]=a0.w;
        if constexpr (DIFF) {
            float4 b0 = *(const float4*)(pb + off);
            b[0]=b0.x; b[1]=b0.y; b[2]=b0.z; b[3]=b0.w;
        }
    } else {
        float2 a0 = *(const float2*)(pa + off);
        a[0]=a0.x; a[1]=a0.y;
        if constexpr (DIFF) {
            float2 b0 = *(const float2*)(pb + off);
            b[0]=b0.x; b[1]=b0.y;
        }
    }
}

template<int NC, bool DIFF>
__device__ __forceinline__ void materialize(const float* __restrict__ a,
                                            const float* __restrict__ b,
                                            float* __restrict__ c) {
#pragma unroll
    for (int i = 0; i < NC; ++i) c[i] = DIFF ? (a[i] - b[i]) : a[i];
}

// horizontal 5-tap at even cols. c = own NC cols; o = ND outputs.
template<int NC>
__device__ __forceinline__ void hconv(const float* __restrict__ c,
                                      float* __restrict__ o, int lane) {
    constexpr int ND = NC / 2;
    float e[NC + 3];
#pragma unroll
    for (int i = 0; i < NC; ++i) e[i + 2] = c[i];
    const bool l0 = (lane == 0), l63 = (lane == 63);
    { float v = __shfl(e[NC + 1], lane - 1); e[1] = l0 ? e[3] : v; }
    if constexpr (NC >= 4) {
        { float v = __shfl(e[NC], lane - 1); e[0] = l0 ? e[4] : v; }
        { float v = __shfl(e[2], lane + 1); e[NC + 2] = l63 ? e[NC] : v; }
    } else {
        e[0] = __shfl(e[2], l0 ? 1 : lane - 1);
        e[NC + 2] = __shfl(e[2], l63 ? 63 : lane + 1);
    }
#pragma unroll
    for (int j = 0; j < ND; ++j)
        o[j] = KA * e[2*j] + KB * e[2*j+1] + KC * e[2*j+2]
             + KB * e[2*j+3] + KA * e[2*j+4];
}

// One R-row strip of one level: band L1-sum returned; down rows written to
// pd (row stride DS). Verified algebra (R3/R4, absmax 0). PD = prefetch depth.
template<int H, int NC, int R, int SS, int DS, bool DIFF, int PD>
__device__ __forceinline__ float slide_strip(
        const float* __restrict__ pa, const float* __restrict__ pb,
        float* __restrict__ pd, int lane, int y0) {
    constexpr int ND = NC / 2;
    const int basec = lane * NC;

    float h0[ND], h1[ND], h2[ND], h3[ND], h4[ND];
    float wPrev[NC], pA[NC], pB[NC], pC[NC];  // pending band state
    float UA1[NC], UA2[NC];                   // prefetch bank U
    float UB1[DIFF ? NC : 1], UB2[DIFF ? NC : 1];
    float VA1[PD == 2 ? NC : 1], VA2[PD == 2 ? NC : 1];  // bank V (PD=2)
    float VB1[(PD == 2 && DIFF) ? NC : 1], VB2[(PD == 2 && DIFF) ? NC : 1];
#pragma unroll
    for (int i = 0; i < NC; ++i) {
        wPrev[i] = 0.f; pA[i] = 0.f; pB[i] = 0.f; pC[i] = 0.f;
    }
    float acc = 0.f;

    const int d0 = y0 >> 1;
    const int db = d0 - 1;   // uniform start (reflection makes W[-1]=W[1])

    // prologue: h-ring rows 2db-2, 2db-1, 2db
    {
        float t[NC], tb[DIFF ? NC : 1], c[NC];
        load_raw<SS,NC,DIFF>(pa, pb, refl(2*db - 2, H), basec, t, tb);
        materialize<NC,DIFF>(t, tb, c); hconv<NC>(c, h0, lane);
        load_raw<SS,NC,DIFF>(pa, pb, refl(2*db - 1, H), basec, t, tb);
        materialize<NC,DIFF>(t, tb, c); hconv<NC>(c, h1, lane);
        load_raw<SS,NC,DIFF>(pa, pb, refl(2*db, H), basec, t, tb);
        materialize<NC,DIFF>(t, tb, c); hconv<NC>(c, h2, lane);
    }
    // fill banks: U <- rows for first body (and V <- second, PD=2)
    load_raw<SS,NC,DIFF>(pa, pb, refl(2*db + 1, H), basec, UA1, UB1);
    load_raw<SS,NC,DIFF>(pa, pb, refl(2*db + 2, H), basec, UA2, UB2);
    if constexpr (PD == 2) {
        load_raw<SS,NC,DIFF>(pa, pb, refl(2*db + 3, H), basec, VA1, VB1);
        load_raw<SS,NC,DIFF>(pa, pb, refl(2*db + 4, H), basec, VA2, VB2);
    }

    // one iteration body. Bank consumed here was loaded PD bodies ago.
    auto body = [&](int d, float* A1, float* A2, float* B1, float* B2,
                    bool doFin, bool doStore, bool doIssue) {
        float c1[NC], c2[NC];
        materialize<NC,DIFF>(A1, B1, c1);   // raw row 2d+1
        materialize<NC,DIFF>(A2, B2, c2);   // raw row 2d+2
        if (doIssue) {                      // refill for iter d+PD
            load_raw<SS,NC,DIFF>(pa, pb, refl(2*d + 2*PD + 1, H), basec, A1, B1);
            load_raw<SS,NC,DIFF>(pa, pb, refl(2*d + 2*PD + 2, H), basec, A2, B2);
        }
        hconv<NC>(c1, h3, lane);
        hconv<NC>(c2, h4, lane);

        float dn[ND];
#pragma unroll
        for (int j = 0; j < ND; ++j)
            dn[j] = KA*h0[j] + KB*h1[j] + KC*h2[j] + KB*h3[j] + KA*h4[j];

        if (doStore) {
            const int doff = d * DS + lane * ND;
            if constexpr (ND == 4) {
                float4 s; s.x=dn[0]; s.y=dn[1]; s.z=dn[2]; s.w=dn[3];
                *(float4*)(pd + doff) = s;
            } else if constexpr (ND == 2) {
                float2 s; s.x=dn[0]; s.y=dn[1];
                *(float2*)(pd + doff) = s;
            } else {
                pd[doff] = dn[0];
            }
        }

        // horizontal-up row W[d] -> wN
        float dm, dp;
        if constexpr (ND >= 2) {
            { float v = __shfl(dn[ND-1], lane - 1); dm = (lane == 0)  ? dn[1]    : v; }
            { float v = __shfl(dn[0],    lane + 1); dp = (lane == 63) ? dn[ND-1] : v; }
        } else {
            dm = __shfl(dn[0], (lane == 0)  ? 1  : lane - 1);
            dp = __shfl(dn[0], (lane == 63) ? 63 : lane + 1);
        }
        float wN[NC];
#pragma unroll
        for (int j = 0; j < ND; ++j) {
            float lf = j ? dn[j-1] : dm;
            float rg = (j + 1 < ND) ? dn[j+1] : dp;
            wN[2*j]     = 0.125f * lf + 0.75f * dn[j] + 0.125f * rg;
            wN[2*j + 1] = 0.5f * (dn[j] + rg);
        }

        // finalize band rows 2d-2 (even, pA) and 2d-1 (odd, pB).
        if (doFin) {
#pragma unroll
            for (int i = 0; i < NC; ++i) {
                acc += fabsf(pA[i] - (0.75f*wPrev[i] + 0.125f*wN[i]));
                acc += fabsf(pB[i] - 0.5f*wN[i]);
            }
        }

        // create next pending state + shift rings
#pragma unroll
        for (int i = 0; i < NC; ++i) {
            pA[i] = pC[i];
            pC[i] = c2[i] - 0.125f * wN[i];   // even row 2d+2 - 0.125*W[d]
            pB[i] = c1[i] - 0.5f   * wN[i];   // odd  row 2d+1 - 0.5*W[d]
            wPrev[i] = wN[i];
        }
#pragma unroll
        for (int j = 0; j < ND; ++j) { h0[j] = h2[j]; h1[j] = h3[j]; h2[j] = h4[j]; }
    };

    if constexpr (PD == 1) {
        // bodies k=0..R/2+1, d = db+k
#pragma unroll
        for (int k = 0; k < R/2 + 2; ++k) {
            body(db + k, UA1, UA2, UB1, UB2,
                 k >= 2,                 // fin: d >= d0+1
                 k >= 1 && k < R/2 + 1,  // store: d in [d0, d0+R/2)
                 k < R/2 + 1);           // issue: d < dend
        }
    } else {
        constexpr int CNT2 = R / 4 + 1;
#pragma unroll
        for (int i = 0; i < CNT2; ++i) {
            const bool fin = (i >= 1);
            const bool iss = (i < CNT2 - 1);
            body(db + 2*i,     UA1, UA2, UB1, UB2, fin, i >= 1,       iss);
            body(db + 2*i + 1, VA1, VA2, VB1, VB2, fin, i < CNT2 - 1, iss);
        }
    }
    return acc;
}

// ---- level 0: global->global, 4 waves/block, one strip per wave ----
template<int H, int NC, bool DIFF, int R>
__global__ __launch_bounds__(256) void lap_slide(
        const float* __restrict__ A, const float* __restrict__ B,
        float* __restrict__ down, float* __restrict__ out, float invN) {
    constexpr int Hd = H / 2, SPP = H / R;
    __shared__ float red[4];
    const int tid = threadIdx.x;
    const int lane = tid & 63, wid = tid >> 6;
    const int sid = blockIdx.x * 4 + wid;
    const int bc = sid / SPP;
    const int y0 = (sid % SPP) * R;
    const float* pa = A + (size_t)bc * H * H;
    const float* pb = DIFF ? (B + (size_t)bc * H * H) : nullptr;
    float* pd = down + (size_t)bc * Hd * Hd;

    float acc = slide_strip<H, NC, R, H, Hd, DIFF, 2>(pa, pb, pd, lane, y0);

#pragma unroll
    for (int off2 = 32; off2 > 0; off2 >>= 1)
        acc += __shfl_down(acc, off2, 64);
    if (lane == 0) red[wid] = acc;
    __syncthreads();
    if (tid == 0)
        atomicAdd(out, (red[0] + red[1] + red[2] + red[3]) * invN);
}

// ---- levels 1..4 fused: one 1024-thr block per plane ----
__global__ __launch_bounds__(1024) void lap_rest(
        const float* __restrict__ down0, float* __restrict__ out,
        float invN1, float invN2, float invN3, float invN4) {
    __shared__ float d1[128 * 128];   // down1 (level-1 output)
    __shared__ float p[64 * 66];      // down2, padded (lap_small layout)
    __shared__ float hh[64 * 34];
    __shared__ float dd[32 * 34];
    __shared__ float W3[32 * 64];
    __shared__ float h4[32 * 18];
    __shared__ float d4[16 * 18];
    __shared__ float W4[16 * 32];
    __shared__ float red[16];
    const int tid = threadIdx.x;
    const int lane = tid & 63, wid = tid >> 6;   // 16 waves
    const float* src = down0 + (size_t)blockIdx.x * 65536;

    // L1: H=256, NC=4, R=16 strips; src global (stride 256) -> d1 (stride 128)
    float acc = invN1 *
        slide_strip<256, 4, 16, 256, 128, false, 1>(src, nullptr, d1, lane, wid * 16);
    __syncthreads();
    // L2: H=128, NC=2, R=8 strips; src d1 (stride 128) -> p (stride 66, ND=1)
    acc += invN2 *
        slide_strip<128, 2, 8, 128, 66, false, 1>(d1, nullptr, p, lane, wid * 8);
    __syncthreads();

    // L3/L4: verified lap_small code on p
    const float k[5] = {KA, KB, KC, KB, KA};
    for (int i = tid; i < 64 * 32; i += 1024) {
        int r = i >> 5, t = i & 31;
        const float* pr = p + r * 66;
        float s = 0.f;
#pragma unroll
        for (int v = 0; v < 5; ++v) s += k[v] * pr[refl(2*t + v - 2, 64)];
        hh[r * 34 + t] = s;
    }
    __syncthreads();
    for (int i = tid; i < 32 * 32; i += 1024) {
        int dy = i >> 5, t = i & 31;
        float s = 0.f;
#pragma unroll
        for (int u = 0; u < 5; ++u) s += k[u] * hh[refl(2*dy + u - 2, 64) * 34 + t];
        dd[dy * 34 + t] = s;
    }
    __syncthreads();
    for (int i = tid; i < 32 * 32; i += 1024) {
        int a = i >> 5, t = i & 31;
        const float* dr = dd + a * 34;
        float dm = dr[t == 0 ? 1 : t - 1];
        float dc = dr[t];
        float dp = dr[t == 31 ? 31 : t + 1];
        W3[a * 64 + 2*t]     = 0.125f * dm + 0.75f * dc + 0.125f * dp;
        W3[a * 64 + 2*t + 1] = 0.5f * (dc + dp);
    }
    __syncthreads();
    float acc3 = 0.f;
    for (int i = tid; i < 4096; i += 1024) {
        int y = i >> 6, x = i & 63;
        float cur = p[y * 66 + x];
        float up;
        if ((y & 1) == 0) {
            int a0 = refl(y - 2, 64) >> 1, a1 = y >> 1, a2 = refl(y + 2, 64) >> 1;
            up = 0.125f*W3[a0*64 + x] + 0.75f*W3[a1*64 + x] + 0.125f*W3[a2*64 + x];
        } else {
            int a0 = (y - 1) >> 1, a1 = refl(y + 1, 64) >> 1;
            up = 0.5f * (W3[a0*64 + x] + W3[a1*64 + x]);
        }
        acc3 += fabsf(cur - up);
    }
    __syncthreads();
    for (int i = tid; i < 32 * 16; i += 1024) {
        int r = i >> 4, t = i & 15;
        const float* pr = dd + r * 34;
        float s = 0.f;
#pragma unroll
        for (int v = 0; v < 5; ++v) s += k[v] * pr[refl(2*t + v - 2, 32)];
        h4[r * 18 + t] = s;
    }
    __syncthreads();
    for (int i = tid; i < 16 * 16; i += 1024) {
        int dy = i >> 4, t = i & 15;
        float s = 0.f;
#pragma unroll
        for (int u = 0; u < 5; ++u) s += k[u] * h4[refl(2*dy + u - 2, 32) * 18 + t];
        d4[dy * 18 + t] = s;
    }
    __syncthreads();
    for (int i = tid; i < 16 * 16; i += 1024) {
        int a = i >> 4, t = i & 15;
        const float* dr = d4 + a * 18;
        float dm = dr[t == 0 ? 1 : t - 1];
        float dc = dr[t];
        float dp = dr[t == 15 ? 15 : t + 1];
        W4[a * 32 + 2*t]     = 0.125f * dm + 0.75f * dc + 0.125f * dp;
        W4[a * 32 + 2*t + 1] = 0.5f * (dc + dp);
    }
    __syncthreads();
    float acc4 = 0.f;
    for (int i = tid; i < 1024; i += 1024) {
        int y = i >> 5, x = i & 31;
        float cur = dd[y * 34 + x];
        float up;
        if ((y & 1) == 0) {
            int a0 = refl(y - 2, 32) >> 1, a1 = y >> 1, a2 = refl(y + 2, 32) >> 1;
            up = 0.125f*W4[a0*32 + x] + 0.75f*W4[a1*32 + x] + 0.125f*W4[a2*32 + x];
        } else {
            int a0 = (y - 1) >> 1, a1 = refl(y + 1, 32) >> 1;
            up = 0.5f * (W4[a0*32 + x] + W4[a1*32 + x]);
        }
        acc4 += fabsf(cur - up);
    }
    acc += acc3 * invN3 + acc4 * invN4;

#pragma unroll
    for (int off2 = 32; off2 > 0; off2 >>= 1)
        acc += __shfl_down(acc, off2, 64);
    if (lane == 0) red[wid] = acc;
    __syncthreads();
    if (tid == 0) {
        float s = 0.f;
#pragma unroll
        for (int i = 0; i < 16; ++i) s += red[i];
        atomicAdd(out, s);
    }
}

extern "C" void kernel_launch(void* const* d_in, const int* in_sizes, int n_in,
                              void* d_out, int out_size, void* d_ws, size_t ws_size,
                              hipStream_t stream) {
    const float* in = (const float*)d_in[0];
    const float* tg = (const float*)d_in[1];
    float* out = (float*)d_out;
    float* ws = (float*)d_ws;

    float* down0 = ws;   // 96*256*256 floats

    hipMemsetAsync(out, 0, sizeof(float), stream);

    // level 0: R=16 -> 96*32 strips, depth-2 prefetch (unchanged control)
    lap_slide<512, 8, true, 16><<<96 * 32 / 4, 256, 0, stream>>>(
        in, tg, down0, out, 1.f / (96.f * 512.f * 512.f));
    // levels 1-4 fused: one block per plane, depth-1 prefetch (spill fix)
    lap_rest<<<BC, 1024, 0, stream>>>(
        down0, out,
        1.f / (96.f * 256.f * 256.f), 1.f / (96.f * 128.f * 128.f),
        1.f / (96.f * 64.f * 64.f),  1.f / (96.f * 32.f * 32.f));
}